// Round 4
// baseline (63.805 us; speedup 1.0000x reference)
//
#include <hip/hip_runtime.h>
#include <hip/hip_fp16.h>
#include <math.h>

#define U 50
#define TT 100
#define BB 256

typedef _Float16 half2v __attribute__((ext_vector_type(2)));

__device__ __forceinline__ float dot2_acc(half2v a, half2v b, float c) {
#if __has_builtin(__builtin_amdgcn_fdot2)
    return __builtin_amdgcn_fdot2(a, b, c, false);
#else
    return fmaf((float)a.x, (float)b.x, fmaf((float)a.y, (float)b.y, c));
#endif
}

__device__ __forceinline__ float sigmoid_fast(float x) {
    return 1.0f / (1.0f + __expf(-x));
}
__device__ __forceinline__ float tanh_fast(float x) {
    float e = __expf(2.0f * x);
    return 1.0f - 2.0f / (e + 1.0f);
}
__device__ __forceinline__ float param_act(float x, float mn, float mx) {
    float scale = 0.5f * (mx - mn);
    return tanh_fast(x) * scale + mn + scale;
}

// One wave per batch element. Lane l (<50) owns LSTM unit l; the four gate
// columns of rec live as 100 PACKED f16 pairs in registers (v_dot2_f32_f16,
// f32 accumulate). h is exchanged as f16 through LDS (1 ds_write_b16 +
// 7 broadcast reads). Single wave -> no barriers ever.
__global__ __launch_bounds__(64, 1) void encoder_kernel(
    const float* __restrict__ x,        // (B,T,4)
    const float* __restrict__ state,    // (B,T,4)
    const float* __restrict__ kernel,   // (4,200)
    const float* __restrict__ rec,      // (50,200)
    const float* __restrict__ bias,     // (200,)
    const float* __restrict__ w_dv, const float* __restrict__ b_dv,
    const float* __restrict__ w_dt, const float* __restrict__ b_dt,
    const float* __restrict__ w_mj, const float* __restrict__ b_mj,
    const float* __restrict__ w_ma, const float* __restrict__ b_ma,
    const float* __restrict__ w_mi, const float* __restrict__ b_mi,
    float* __restrict__ out)            // act_seq (B*T) then idm (B*5)
{
    const int b = blockIdx.x;
    const int l = threadIdx.x;
    const int cl = (l < U) ? l : (U - 1);   // clamped column (no per-weight cndmask)

    __shared__ __align__(16) _Float16 h16[64];  // 50 used, rest stays 0
    __shared__ float idm[8];

    // rcp[g*25+j] = (rec[2j][g*50+cl], rec[2j+1][g*50+cl]) packed f16
    half2v rcp[100];
    #pragma unroll
    for (int g = 0; g < 4; ++g) {
        #pragma unroll
        for (int j = 0; j < 25; ++j) {
            float a = rec[(2 * j) * 200 + g * U + cl];
            float c = rec[(2 * j + 1) * 200 + g * U + cl];
            half2v p; p.x = (_Float16)a; p.y = (_Float16)c;
            rcp[g * 25 + j] = p;
        }
    }

    float kc[16];
    #pragma unroll
    for (int g = 0; g < 4; ++g)
        #pragma unroll
        for (int f = 0; f < 4; ++f)
            kc[g * 4 + f] = kernel[f * 200 + g * U + cl];

    float bz[4];
    #pragma unroll
    for (int g = 0; g < 4; ++g) bz[g] = bias[g * U + cl];

    h16[l] = (_Float16)0.0f;
    float c = 0.0f;

    const float4* __restrict__ xb4 = (const float4*)(x + (size_t)b * TT * 4);
    const half2v* __restrict__ hp = (const half2v*)h16;

    float4 x4 = xb4[0];

    for (int t = 0; t < TT; ++t) {
        float4 x4n = xb4[(t + 1 < TT) ? (t + 1) : t];  // prefetch

        // Load all 25 packed h pairs first (6x ds_read_b128 + 1x b32 broadcast)
        half2v hv[25];
        #pragma unroll
        for (int j = 0; j < 25; ++j) hv[j] = hp[j];

        // x-part (independent of h -> fills the LDS latency shadow)
        float zx[4];
        #pragma unroll
        for (int g = 0; g < 4; ++g) {
            zx[g] = fmaf(x4.x, kc[g * 4 + 0],
                    fmaf(x4.y, kc[g * 4 + 1],
                    fmaf(x4.z, kc[g * 4 + 2],
                    fmaf(x4.w, kc[g * 4 + 3], bz[g]))));
        }

        // 100 v_dot2_f32_f16, 8 interleaved accumulator chains
        float acc[8] = {0.f, 0.f, 0.f, 0.f, 0.f, 0.f, 0.f, 0.f};
        #pragma unroll
        for (int j = 0; j < 25; ++j) {
            const int s = (j & 1) * 4;
            acc[s + 0] = dot2_acc(hv[j], rcp[0 * 25 + j], acc[s + 0]);
            acc[s + 1] = dot2_acc(hv[j], rcp[1 * 25 + j], acc[s + 1]);
            acc[s + 2] = dot2_acc(hv[j], rcp[2 * 25 + j], acc[s + 2]);
            acc[s + 3] = dot2_acc(hv[j], rcp[3 * 25 + j], acc[s + 3]);
        }

        float zi = zx[0] + acc[0] + acc[4];
        float zf = zx[1] + acc[1] + acc[5];
        float zg = zx[2] + acc[2] + acc[6];
        float zo = zx[3] + acc[3] + acc[7];

        float ig = sigmoid_fast(zi);
        float fg = sigmoid_fast(zf);
        float gg = tanh_fast(zg);
        float og = sigmoid_fast(zo);
        c = fmaf(fg, c, ig * gg);
        float hnew = og * tanh_fast(c);
        if (l < U) h16[l] = (_Float16)hnew;
        x4 = x4n;
        // no barrier: single wave, in-order LDS pipeline + compiler lgkmcnt
    }

    // ---- 5 output heads (lanes 0..4) ----
    if (l < 5) {
        const float* w  = (l == 0) ? w_dv : (l == 1) ? w_dt :
                          (l == 2) ? w_mj : (l == 3) ? w_ma : w_mi;
        const float* bb = (l == 0) ? b_dv : (l == 1) ? b_dt :
                          (l == 2) ? b_mj : (l == 3) ? b_ma : b_mi;
        float s = bb[0];
        #pragma unroll
        for (int j = 0; j < U; ++j) s = fmaf((float)h16[j], w[j], s);
        float v;
        if (l == 0)      v = param_act(s, 15.0f, 35.0f);
        else if (l == 1) v = param_act(s, 0.5f, 3.0f);
        else if (l == 2) v = fmaxf(s, 0.0f);
        else if (l == 3) v = param_act(s, 0.5f, 3.0f);
        else             v = param_act(s, 0.5f, 4.0f);
        idm[l] = v;
        out[BB * TT + b * 5 + l] = v;
    }

    // ---- IDM physics over T ----
    const float desired_v    = idm[0];
    const float desired_tgap = idm[1];
    const float min_jamx     = idm[2];
    const float max_act      = idm[3];
    const float min_act      = idm[4];
    const float inv_tsab = 1.0f / (2.0f * sqrtf(max_act * min_act));
    const float inv_dv   = 1.0f / desired_v;

    const float4* __restrict__ sb4 = (const float4*)(state + (size_t)b * TT * 4);
    for (int t = l; t < TT; t += 64) {
        float4 s4 = sb4[t];
        float vel = s4.x;
        float dv  = s4.z;
        float dx  = s4.w;
        float dgap = fmaf(desired_tgap, vel, fmaf(vel * dv, inv_tsab, min_jamx));
        float r1 = vel * inv_dv;
        r1 = r1 * r1;
        r1 = r1 * r1;            // ^4
        float r2 = dgap / dx;
        r2 = r2 * r2;            // ^2
        out[b * TT + t] = max_act * (1.0f - (r1 + r2));
    }
}

extern "C" void kernel_launch(void* const* d_in, const int* in_sizes, int n_in,
                              void* d_out, int out_size, void* d_ws, size_t ws_size,
                              hipStream_t stream) {
    const float* x      = (const float*)d_in[0];
    const float* state  = (const float*)d_in[1];
    const float* kern   = (const float*)d_in[2];
    const float* rec    = (const float*)d_in[3];
    const float* bias   = (const float*)d_in[4];
    const float* w_dv   = (const float*)d_in[5];
    const float* b_dv   = (const float*)d_in[6];
    const float* w_dt   = (const float*)d_in[7];
    const float* b_dt   = (const float*)d_in[8];
    const float* w_mj   = (const float*)d_in[9];
    const float* b_mj   = (const float*)d_in[10];
    const float* w_ma   = (const float*)d_in[11];
    const float* b_ma   = (const float*)d_in[12];
    const float* w_mi   = (const float*)d_in[13];
    const float* b_mi   = (const float*)d_in[14];
    float* out = (float*)d_out;

    encoder_kernel<<<BB, 64, 0, stream>>>(
        x, state, kern, rec, bias,
        w_dv, b_dv, w_dt, b_dt, w_mj, b_mj, w_ma, b_ma, w_mi, b_mi,
        out);
}

// Round 5
// 54.723 us; speedup vs baseline: 1.1660x; 1.1660x over previous
//
#include <hip/hip_runtime.h>
#include <hip/hip_fp16.h>
#include <math.h>
#include <stdint.h>

#define U 50
#define TT 100
#define BB 256

typedef _Float16 half2v __attribute__((ext_vector_type(2)));

__device__ __forceinline__ float dot2_acc(half2v a, half2v b, float c) {
#if __has_builtin(__builtin_amdgcn_fdot2)
    return __builtin_amdgcn_fdot2(a, b, c, false);
#else
    return fmaf((float)a.x, (float)b.x, fmaf((float)a.y, (float)b.y, c));
#endif
}

__device__ __forceinline__ float sigmoid_fast(float x) {
    return 1.0f / (1.0f + __expf(-x));
}
__device__ __forceinline__ float tanh_fast(float x) {
    float e = __expf(2.0f * x);
    return 1.0f - 2.0f / (e + 1.0f);
}
__device__ __forceinline__ float param_act(float x, float mn, float mx) {
    float scale = 0.5f * (mx - mn);
    return tanh_fast(x) * scale + mn + scale;
}

// One wave per batch element. Lane l (<50) owns LSTM unit l; the four gate
// columns of rec live as 100 packed-f16 uint32 registers, PINNED via empty
// asm ("+v") so the compiler cannot rematerialize/spill them (rounds 2-3
// failure mode: VGPR_Count 144/80 showed weights never stayed resident).
__global__ __launch_bounds__(64, 1) void encoder_kernel(
    const float* __restrict__ x,        // (B,T,4)
    const float* __restrict__ state,    // (B,T,4)
    const float* __restrict__ kernel,   // (4,200)
    const float* __restrict__ rec,      // (50,200)
    const float* __restrict__ bias,     // (200,)
    const float* __restrict__ w_dv, const float* __restrict__ b_dv,
    const float* __restrict__ w_dt, const float* __restrict__ b_dt,
    const float* __restrict__ w_mj, const float* __restrict__ b_mj,
    const float* __restrict__ w_ma, const float* __restrict__ b_ma,
    const float* __restrict__ w_mi, const float* __restrict__ b_mi,
    float* __restrict__ out)            // act_seq (B*T) then idm (B*5)
{
    const int b = blockIdx.x;
    const int l = threadIdx.x;
    const int cl = (l < U) ? l : (U - 1);   // clamped column (no per-weight cndmask)

    __shared__ __align__(16) _Float16 h16[64];  // 50 used, rest stays 0
    __shared__ float idm[8];

    // rcpu[g*25+j] = packed( rec[2j][g*50+cl], rec[2j+1][g*50+cl] )
    uint32_t rcpu[100];
    #pragma unroll
    for (int g = 0; g < 4; ++g) {
        #pragma unroll
        for (int j = 0; j < 25; ++j) {
            float a = rec[(2 * j) * 200 + g * U + cl];
            float c2 = rec[(2 * j + 1) * 200 + g * U + cl];
            half2v p; p.x = (_Float16)a; p.y = (_Float16)c2;
            rcpu[g * 25 + j] = __builtin_bit_cast(uint32_t, p);
        }
    }
    // PIN: empty asm "writes" each reg -> no rematerialization possible.
    #pragma unroll
    for (int j = 0; j < 100; ++j) asm volatile("" : "+v"(rcpu[j]));

    float kc[16];
    #pragma unroll
    for (int g = 0; g < 4; ++g)
        #pragma unroll
        for (int f = 0; f < 4; ++f)
            kc[g * 4 + f] = kernel[f * 200 + g * U + cl];
    #pragma unroll
    for (int j = 0; j < 16; ++j) asm volatile("" : "+v"(kc[j]));

    float bz[4];
    #pragma unroll
    for (int g = 0; g < 4; ++g) bz[g] = bias[g * U + cl];
    #pragma unroll
    for (int g = 0; g < 4; ++g) asm volatile("" : "+v"(bz[g]));

    h16[l] = (_Float16)0.0f;
    float c = 0.0f;

    const float4* __restrict__ xb4 = (const float4*)(x + (size_t)b * TT * 4);
    const half2v* __restrict__ hp = (const half2v*)h16;

    float4 x4 = xb4[0];

    // software-pipelined h fragment (all zeros for t=0)
    half2v hv[25];
    #pragma unroll
    for (int j = 0; j < 25; ++j) hv[j] = hp[j];

    for (int t = 0; t < TT; ++t) {
        float4 x4n = xb4[(t + 1 < TT) ? (t + 1) : t];  // prefetch

        // x-part (independent of h)
        float zx[4];
        #pragma unroll
        for (int g = 0; g < 4; ++g) {
            zx[g] = fmaf(x4.x, kc[g * 4 + 0],
                    fmaf(x4.y, kc[g * 4 + 1],
                    fmaf(x4.z, kc[g * 4 + 2],
                    fmaf(x4.w, kc[g * 4 + 3], bz[g]))));
        }

        // 100 v_dot2_f32_f16, 8 interleaved accumulator chains
        float acc[8] = {0.f, 0.f, 0.f, 0.f, 0.f, 0.f, 0.f, 0.f};
        #pragma unroll
        for (int j = 0; j < 25; ++j) {
            const int s = (j & 1) * 4;
            acc[s + 0] = dot2_acc(hv[j], __builtin_bit_cast(half2v, rcpu[0 * 25 + j]), acc[s + 0]);
            acc[s + 1] = dot2_acc(hv[j], __builtin_bit_cast(half2v, rcpu[1 * 25 + j]), acc[s + 1]);
            acc[s + 2] = dot2_acc(hv[j], __builtin_bit_cast(half2v, rcpu[2 * 25 + j]), acc[s + 2]);
            acc[s + 3] = dot2_acc(hv[j], __builtin_bit_cast(half2v, rcpu[3 * 25 + j]), acc[s + 3]);
        }

        float zi = zx[0] + acc[0] + acc[4];
        float zf = zx[1] + acc[1] + acc[5];
        float zg = zx[2] + acc[2] + acc[6];
        float zo = zx[3] + acc[3] + acc[7];

        float ig = sigmoid_fast(zi);
        float fg = sigmoid_fast(zf);
        float gg = tanh_fast(zg);
        float og = sigmoid_fast(zo);
        c = fmaf(fg, c, ig * gg);
        float hnew = og * tanh_fast(c);
        if (l < U) h16[l] = (_Float16)hnew;

        // immediately re-read h for the next step (latency overlaps next zx)
        #pragma unroll
        for (int j = 0; j < 25; ++j) hv[j] = hp[j];

        x4 = x4n;
        // no barrier: single wave, in-order LDS pipeline + compiler lgkmcnt
    }

    // ---- 5 output heads (lanes 0..4) ----
    if (l < 5) {
        const float* w  = (l == 0) ? w_dv : (l == 1) ? w_dt :
                          (l == 2) ? w_mj : (l == 3) ? w_ma : w_mi;
        const float* bb = (l == 0) ? b_dv : (l == 1) ? b_dt :
                          (l == 2) ? b_mj : (l == 3) ? b_ma : b_mi;
        float s = bb[0];
        #pragma unroll
        for (int j = 0; j < U; ++j) s = fmaf((float)h16[j], w[j], s);
        float v;
        if (l == 0)      v = param_act(s, 15.0f, 35.0f);
        else if (l == 1) v = param_act(s, 0.5f, 3.0f);
        else if (l == 2) v = fmaxf(s, 0.0f);
        else if (l == 3) v = param_act(s, 0.5f, 3.0f);
        else             v = param_act(s, 0.5f, 4.0f);
        idm[l] = v;
        out[BB * TT + b * 5 + l] = v;
    }

    // ---- IDM physics over T ----
    const float desired_v    = idm[0];
    const float desired_tgap = idm[1];
    const float min_jamx     = idm[2];
    const float max_act      = idm[3];
    const float min_act      = idm[4];
    const float inv_tsab = 1.0f / (2.0f * sqrtf(max_act * min_act));
    const float inv_dv   = 1.0f / desired_v;

    const float4* __restrict__ sb4 = (const float4*)(state + (size_t)b * TT * 4);
    for (int t = l; t < TT; t += 64) {
        float4 s4 = sb4[t];
        float vel = s4.x;
        float dv  = s4.z;
        float dx  = s4.w;
        float dgap = fmaf(desired_tgap, vel, fmaf(vel * dv, inv_tsab, min_jamx));
        float r1 = vel * inv_dv;
        r1 = r1 * r1;
        r1 = r1 * r1;            // ^4
        float r2 = dgap / dx;
        r2 = r2 * r2;            // ^2
        out[b * TT + t] = max_act * (1.0f - (r1 + r2));
    }
}

extern "C" void kernel_launch(void* const* d_in, const int* in_sizes, int n_in,
                              void* d_out, int out_size, void* d_ws, size_t ws_size,
                              hipStream_t stream) {
    const float* x      = (const float*)d_in[0];
    const float* state  = (const float*)d_in[1];
    const float* kern   = (const float*)d_in[2];
    const float* rec    = (const float*)d_in[3];
    const float* bias   = (const float*)d_in[4];
    const float* w_dv   = (const float*)d_in[5];
    const float* b_dv   = (const float*)d_in[6];
    const float* w_dt   = (const float*)d_in[7];
    const float* b_dt   = (const float*)d_in[8];
    const float* w_mj   = (const float*)d_in[9];
    const float* b_mj   = (const float*)d_in[10];
    const float* w_ma   = (const float*)d_in[11];
    const float* b_ma   = (const float*)d_in[12];
    const float* w_mi   = (const float*)d_in[13];
    const float* b_mi   = (const float*)d_in[14];
    float* out = (float*)d_out;

    encoder_kernel<<<BB, 64, 0, stream>>>(
        x, state, kern, rec, bias,
        w_dv, b_dv, w_dt, b_dt, w_mj, b_mj, w_ma, b_ma, w_mi, b_mi,
        out);
}